// Round 11
// baseline (321.923 us; speedup 1.0000x reference)
//
#include <hip/hip_runtime.h>
#include <hip/hip_fp16.h>
#include <math.h>

#define N_NODES 50000
#define N_EDGES 800000
#define NUM_GRAPHS 256
#define C_IN 64
#define C_H 128
#define D_COUNT 9
#define LRELU_SLOPE 0.01f
#define TAB_BINS 8192
#define TAB_SCALE 1024.0f                  // bins per unit distance, covers d in [0,8)
#define WEDGES 64                          // edges per wave
#define NCHUNK (N_EDGES / WEDGES)          // 12500 wave-chunks
#define NBUCK ((N_NODES + 255) / 256)      // 196 coarse buckets (col>>8)
#define REGION_CAP 6144                    // per-bucket region capacity (mean 4081, +32 sigma)
#define SCAT_BLK_EDGES 2048

__device__ __forceinline__ float fast_rcp(float x) { return __builtin_amdgcn_rcpf(x); }
__device__ __forceinline__ __half2 u2h2(unsigned int u) { return __builtin_bit_cast(__half2, u); }
__device__ __forceinline__ unsigned int h22u(__half2 h) { return __builtin_bit_cast(unsigned int, h); }

// ---------------- fast zero: grid-stride uint4 stores (rocclr fill runs at 8% occupancy) ---
__global__ __launch_bounds__(256) void zero_kernel(uint4* __restrict__ p, int n16) {
    const int stride = gridDim.x * 256;
    for (int i = blockIdx.x * 256 + threadIdx.x; i < n16; i += stride)
        p[i] = make_uint4(0u, 0u, 0u, 0u);
}

// ---------------- bucketed CSR build (once; edge structure shared by all 3 layers) ---------
__global__ __launch_bounds__(256) void bscatter_kernel(
        const int* __restrict__ row, const int* __restrict__ col,
        const float* __restrict__ pos, int* __restrict__ bcur, uint2* __restrict__ ebuf) {
    __shared__ int lhist[NBUCK];
    __shared__ int lcur[NBUCK];
    const int t = threadIdx.x;
    const int e0 = blockIdx.x * SCAT_BLK_EDGES;
    for (int i = t; i < NBUCK; i += 256) lhist[i] = 0;
    __syncthreads();

    int myb[8];
    uint2 myrec[8];
#pragma unroll
    for (int s = 0; s < 8; ++s) {
        const int e = e0 + s * 256 + t;
        if (e < N_EDGES) {
            const int r = row[e];
            const int c = col[e];
            const float dx = pos[r * 3 + 0] - pos[c * 3 + 0];
            const float dy = pos[r * 3 + 1] - pos[c * 3 + 1];
            const float dz = pos[r * 3 + 2] - pos[c * 3 + 2];
            const float d = sqrtf(dx * dx + dy * dy + dz * dz);
            int bin = (int)(d * TAB_SCALE);
            bin = bin < TAB_BINS - 1 ? bin : TAB_BINS - 1;  // radial saturates beyond table
            myb[s] = c >> 8;
            myrec[s] = make_uint2((unsigned int)r | ((unsigned int)c << 16),
                                  (unsigned int)bin);
            atomicAdd(&lhist[myb[s]], 1);
        } else {
            myb[s] = -1;
        }
    }
    __syncthreads();
    for (int i = t; i < NBUCK; i += 256)
        lcur[i] = (lhist[i] > 0) ? atomicAdd(&bcur[i], lhist[i]) : 0;
    __syncthreads();
#pragma unroll
    for (int s = 0; s < 8; ++s) {
        if (myb[s] >= 0) {
            const int p = atomicAdd(&lcur[myb[s]], 1);
            ebuf[(size_t)myb[s] * REGION_CAP + p] = myrec[s];
        }
    }
}

__global__ void bscan_kernel(const int* __restrict__ bcur, int* __restrict__ bofs) {
    __shared__ int s[256];
    const int t = threadIdx.x;
    const int v = (t < NBUCK) ? bcur[t] : 0;
    s[t] = v;
    __syncthreads();
    for (int d = 1; d < 256; d <<= 1) {
        const int x = (t >= d) ? s[t - d] : 0;
        __syncthreads();
        s[t] += x;
        __syncthreads();
    }
    if (t < NBUCK) bofs[t] = s[t] - v;
    if (t == 0) bofs[NBUCK] = N_EDGES;
}

__global__ __launch_bounds__(256) void bsort_kernel(
        const uint2* __restrict__ ebuf, const int* __restrict__ bcur,
        const int* __restrict__ bofs, uint2* __restrict__ rcb) {
    __shared__ uint2 se[REGION_CAP];   // 48 KB
    __shared__ int lhist[256];
    __shared__ int lcur[256];
    const int b = blockIdx.x;
    const int t = threadIdx.x;
    const int n = bcur[b];
    const uint2* src = ebuf + (size_t)b * REGION_CAP;
    for (int i = t; i < n; i += 256) se[i] = src[i];
    lhist[t] = 0;
    __syncthreads();
    for (int i = t; i < n; i += 256)
        atomicAdd(&lhist[(se[i].x >> 16) & 255u], 1);
    __syncthreads();
    int v = lhist[t];
    int sv = v;
    lcur[t] = v;
    __syncthreads();
    for (int d = 1; d < 256; d <<= 1) {
        const int x = (t >= d) ? lcur[t - d] : 0;
        __syncthreads();
        lcur[t] += x;
        __syncthreads();
        sv = lcur[t];
    }
    __syncthreads();
    lcur[t] = sv - v;  // exclusive
    __syncthreads();
    const int dbase = bofs[b];
    for (int i = t; i < n; i += 256) {
        const uint2 e = se[i];
        const int dst = atomicAdd(&lcur[(e.x >> 16) & 255u], 1);
        rcb[dbase + dst] = e;
    }
}

// ---------------- per-layer radial table: tabh[bin][lane] = half2 radial(d_bin) ------------
__global__ void build_table_kernel(const float* __restrict__ Wc, const float* __restrict__ bc,
                                   unsigned int* __restrict__ tabh) {
    const int idx = blockIdx.x * 256 + threadIdx.x;
    if (idx >= TAB_BINS * 64) return;
    const int lane = idx & 63;
    const int bin = idx >> 6;
    const float d = ((float)bin + 0.5f) * (1.0f / TAB_SCALE);  // bin center (nearest)
    float v[2];
#pragma unroll
    for (int p = 0; p < 2; ++p) {
        const int c = 2 * lane + p;
        float a = bc[c];
#pragma unroll
        for (int k = 0; k < D_COUNT; ++k) {
            const float u = (d - 0.75f * (float)k) * 1.5f;  // mu=0.75k, 1/sigma=1.5
            a = fmaf(__expf(-u * u), Wc[k * C_H + c], a);
        }
        v[p] = a * fast_rcp(1.0f + __expf(-a));
    }
    tabh[idx] = h22u(__floats2half2_rn(v[0], v[1]));
}

// ---------------- hhf = half2(silu(x @ W_lin + b_lin)) -------------------------------------
__global__ __launch_bounds__(256) void lin0_kernel(
        const float* __restrict__ x, const float* __restrict__ W,
        const float* __restrict__ b, unsigned int* __restrict__ hhf) {
    __shared__ float xs[32][C_IN];
    const int node0 = blockIdx.x * 32;
    const int t = threadIdx.x;
    for (int i = t * 4; i < 32 * C_IN; i += 256 * 4) {
        const int n = i >> 6;
        const int c = i & 63;
        if (node0 + n < N_NODES)
            *(float4*)&xs[n][c] = *(const float4*)&x[(size_t)(node0 + n) * C_IN + c];
    }
    __syncthreads();
    const int wv = t >> 6;
    const int lane = t & 63;
    const int nb = wv * 8;
    const float2 b2 = *(const float2*)&b[2 * lane];
    float2 acc[8];
#pragma unroll
    for (int n = 0; n < 8; ++n) acc[n] = b2;
    for (int k = 0; k < C_IN; k += 4) {
        const float2 w0 = *(const float2*)&W[(size_t)(k + 0) * C_H + 2 * lane];
        const float2 w1 = *(const float2*)&W[(size_t)(k + 1) * C_H + 2 * lane];
        const float2 w2 = *(const float2*)&W[(size_t)(k + 2) * C_H + 2 * lane];
        const float2 w3 = *(const float2*)&W[(size_t)(k + 3) * C_H + 2 * lane];
#pragma unroll
        for (int n = 0; n < 8; ++n) {
            const float4 sv = *(const float4*)&xs[nb + n][k];
            acc[n].x = fmaf(sv.x, w0.x, acc[n].x); acc[n].y = fmaf(sv.x, w0.y, acc[n].y);
            acc[n].x = fmaf(sv.y, w1.x, acc[n].x); acc[n].y = fmaf(sv.y, w1.y, acc[n].y);
            acc[n].x = fmaf(sv.z, w2.x, acc[n].x); acc[n].y = fmaf(sv.z, w2.y, acc[n].y);
            acc[n].x = fmaf(sv.w, w3.x, acc[n].x); acc[n].y = fmaf(sv.w, w3.y, acc[n].y);
        }
    }
#pragma unroll
    for (int n = 0; n < 8; ++n) {
        const int node = node0 + nb + n;
        if (node < N_NODES) {
            const float ax = acc[n].x, ay = acc[n].y;
            const float sx = ax * fast_rcp(1.0f + __expf(-ax));
            const float sy = ay * fast_rcp(1.0f + __expf(-ay));
            hhf[(size_t)node * 64 + lane] = h22u(__floats2half2_rn(sx, sy));
        }
    }
}

// ---------------- edge-parallel gather-aggregate (table radial, fp16 h) --------------------
__global__ __launch_bounds__(256) void aggregate_kernel(
        const unsigned int* __restrict__ hhf, const uint2* __restrict__ rcb,
        const unsigned int* __restrict__ tabh, float* __restrict__ agg) {
    __shared__ uint2 meta[4][WEDGES];   // 2 KB/block
    const int t = threadIdx.x;
    const int lane = t & 63;
    const int wv = t >> 6;
    const int base = (blockIdx.x * 4 + wv) * WEDGES;

    const __half2 hzero = __floats2half2_rn(0.0f, 0.0f);

    meta[wv][lane] = rcb[base + lane];
    asm volatile("s_waitcnt lgkmcnt(0)" ::: "memory");
    __builtin_amdgcn_sched_barrier(0);
    __builtin_amdgcn_wave_barrier();

    unsigned int huA[8], huB[8];
    unsigned int tvA[8], tvB[8];
    int colA[8], colB[8];
    __half2 acc2 = hzero;
    float2 accf = make_float2(0.0f, 0.0f);
    int sCur;
    bool first = true;

#define LOADG(g, HU, TV, CO)                                                  \
    {                                                                         \
        _Pragma("unroll")                                                     \
        for (int u = 0; u < 8; ++u) {                                         \
            const uint2 m = meta[wv][(g) * 8 + u];                            \
            const unsigned int rcu = __builtin_amdgcn_readfirstlane(m.x);     \
            const int sBin = __builtin_amdgcn_readfirstlane((int)m.y);        \
            const int sRow = (int)(rcu & 0xffffu);                            \
            CO[u] = (int)(rcu >> 16);                                         \
            HU[u] = hhf[(size_t)sRow * 64 + lane];                            \
            TV[u] = tabh[(size_t)sBin * 64 + lane];                           \
        }                                                                     \
    }

#define COMPUTEG(g, HU, TV, CO)                                               \
    {                                                                         \
        _Pragma("unroll")                                                     \
        for (int u = 0; u < 8; ++u) {                                         \
            if (CO[u] != sCur) {                                              \
                const float2 pf = __half22float2(acc2);                       \
                accf.x += pf.x; accf.y += pf.y; acc2 = hzero;                 \
                float* dst = &agg[(size_t)sCur * C_H + 2 * lane];             \
                if (first) {                                                  \
                    atomicAdd(dst, accf.x); atomicAdd(dst + 1, accf.y);       \
                    first = false;                                            \
                } else {                                                      \
                    dst[0] = accf.x; dst[1] = accf.y;                         \
                }                                                             \
                accf.x = 0.0f; accf.y = 0.0f;                                 \
                sCur = CO[u];                                                 \
            }                                                                 \
            acc2 = __hfma2(u2h2(HU[u]), u2h2(TV[u]), acc2);                   \
        }                                                                     \
        const float2 pg = __half22float2(acc2);                               \
        accf.x += pg.x; accf.y += pg.y; acc2 = hzero;                         \
    }

    LOADG(0, huA, tvA, colA);
    sCur = colA[0];
    LOADG(1, huB, tvB, colB);
    COMPUTEG(0, huA, tvA, colA);
    LOADG(2, huA, tvA, colA);
    COMPUTEG(1, huB, tvB, colB);
    LOADG(3, huB, tvB, colB);
    COMPUTEG(2, huA, tvA, colA);
    LOADG(4, huA, tvA, colA);
    COMPUTEG(3, huB, tvB, colB);
    LOADG(5, huB, tvB, colB);
    COMPUTEG(4, huA, tvA, colA);
    LOADG(6, huA, tvA, colA);
    COMPUTEG(5, huB, tvB, colB);
    LOADG(7, huB, tvB, colB);
    COMPUTEG(6, huA, tvA, colA);
    COMPUTEG(7, huB, tvB, colB);

    {
        float* dst = &agg[(size_t)sCur * C_H + 2 * lane];
        atomicAdd(dst, accf.x);
        atomicAdd(dst + 1, accf.y);
    }
#undef LOADG
#undef COMPUTEG
}

// ---------------- Wn -> half2 pairs ---------------------------------------------------------
__global__ void cvt_wn_kernel(const float* __restrict__ Wn, unsigned int* __restrict__ Wnh) {
    const int i = blockIdx.x * 256 + threadIdx.x;
    if (i < C_H * 64) {
        const int k = i >> 6, p = i & 63;
        Wnh[i] = h22u(__floats2half2_rn(Wn[k * C_H + 2 * p], Wn[k * C_H + 2 * p + 1]));
    }
}

// ---------------- node: h' = g*lrelu((h+agg)@Wn + bn)/sqrt(1+eps)+be; POOL fuses add-pool --
template <int POOL>
__global__ __launch_bounds__(256) void node_kernel(
        unsigned int* __restrict__ hhf, const float2* __restrict__ agg2,
        const unsigned int* __restrict__ Wnh, const float* __restrict__ bn,
        const float* __restrict__ g, const float* __restrict__ be,
        const int* __restrict__ batch, float* __restrict__ out) {
    __shared__ unsigned int s[32][C_H];   // dup half2 per (n,k): 16 KB
    const int node0 = blockIdx.x * 32;
    const int t = threadIdx.x;
    for (int i = t; i < 32 * 64; i += 256) {
        const int n = i >> 6;
        const int p = i & 63;
        if (node0 + n < N_NODES) {
            const float2 hv = __half22float2(u2h2(hhf[(size_t)(node0 + n) * 64 + p]));
            const float2 av = agg2[(size_t)(node0 + n) * 64 + p];
            const float vx = hv.x + av.x;
            const float vy = hv.y + av.y;
            s[n][2 * p]     = h22u(__floats2half2_rn(vx, vx));
            s[n][2 * p + 1] = h22u(__floats2half2_rn(vy, vy));
        }
    }
    __syncthreads();
    const int wv = t >> 6;
    const int lane = t & 63;
    const int nb = wv * 8;
    const float2 bn2 = *(const float2*)&bn[2 * lane];
    const __half2 hzero = __floats2half2_rn(0.0f, 0.0f);
    float2 accf[8];
    __half2 acc2[8];
#pragma unroll
    for (int n = 0; n < 8; ++n) { accf[n] = bn2; acc2[n] = hzero; }
    for (int kb = 0; kb < C_H; kb += 32) {
#pragma unroll
        for (int k4 = 0; k4 < 32; k4 += 4) {
            const int k = kb + k4;
            const unsigned int w0 = Wnh[(size_t)(k + 0) * 64 + lane];
            const unsigned int w1 = Wnh[(size_t)(k + 1) * 64 + lane];
            const unsigned int w2 = Wnh[(size_t)(k + 2) * 64 + lane];
            const unsigned int w3 = Wnh[(size_t)(k + 3) * 64 + lane];
#pragma unroll
            for (int n = 0; n < 8; ++n) {
                const uint4 sv = *(const uint4*)&s[nb + n][k];
                acc2[n] = __hfma2(u2h2(sv.x), u2h2(w0), acc2[n]);
                acc2[n] = __hfma2(u2h2(sv.y), u2h2(w1), acc2[n]);
                acc2[n] = __hfma2(u2h2(sv.z), u2h2(w2), acc2[n]);
                acc2[n] = __hfma2(u2h2(sv.w), u2h2(w3), acc2[n]);
            }
        }
#pragma unroll
        for (int n = 0; n < 8; ++n) {
            const float2 pf = __half22float2(acc2[n]);
            accf[n].x += pf.x; accf[n].y += pf.y;
            acc2[n] = hzero;
        }
    }
    const float inv = 0.9999950000374997f;  // 1/sqrt(1+1e-5)
    float2 g2 = *(const float2*)&g[2 * lane];
    g2.x *= inv; g2.y *= inv;
    const float2 be2 = *(const float2*)&be[2 * lane];
    if (POOL == 0) {
#pragma unroll
        for (int n = 0; n < 8; ++n) {
            const int node = node0 + nb + n;
            if (node < N_NODES) {
                float2 v = accf[n];
                v.x = v.x > 0.0f ? v.x : LRELU_SLOPE * v.x;
                v.y = v.y > 0.0f ? v.y : LRELU_SLOPE * v.y;
                const float ox = fmaf(g2.x, v.x, be2.x);
                const float oy = fmaf(g2.y, v.y, be2.y);
                hhf[(size_t)node * 64 + lane] = h22u(__floats2half2_rn(ox, oy));
            }
        }
    } else {
        float2 pacc = make_float2(0.0f, 0.0f);
        int curb = -1;
#pragma unroll
        for (int n = 0; n < 8; ++n) {
            const int node = node0 + nb + n;
            if (node < N_NODES) {
                float2 v = accf[n];
                v.x = v.x > 0.0f ? v.x : LRELU_SLOPE * v.x;
                v.y = v.y > 0.0f ? v.y : LRELU_SLOPE * v.y;
                const float ox = fmaf(g2.x, v.x, be2.x);
                const float oy = fmaf(g2.y, v.y, be2.y);
                const int bb = batch[node];
                if (bb != curb) {
                    if (curb >= 0) {
                        atomicAdd(&out[curb * C_H + 2 * lane], pacc.x);
                        atomicAdd(&out[curb * C_H + 2 * lane + 1], pacc.y);
                    }
                    pacc = make_float2(0.0f, 0.0f);
                    curb = bb;
                }
                pacc.x += ox;
                pacc.y += oy;
            }
        }
        if (curb >= 0) {
            atomicAdd(&out[curb * C_H + 2 * lane], pacc.x);
            atomicAdd(&out[curb * C_H + 2 * lane + 1], pacc.y);
        }
    }
}

extern "C" void kernel_launch(void* const* d_in, const int* in_sizes, int n_in,
                              void* d_out, int out_size, void* d_ws, size_t ws_size,
                              hipStream_t stream) {
    const float* x     = (const float*)d_in[0];
    const float* pos   = (const float*)d_in[1];
    const int*   eidx  = (const int*)d_in[2];
    const int*   batch = (const int*)d_in[3];
    const float* W_lin = (const float*)d_in[4];
    const float* b_lin = (const float*)d_in[5];

    float* agg = (float*)d_ws;                                         // 25.6 MB
    unsigned int* hhf = (unsigned int*)(agg + (size_t)N_NODES * C_H);  // 12.8 MB
    unsigned int* Wnh  = hhf + (size_t)N_NODES * 64;                   // 32 KB
    unsigned int* tabh = Wnh + C_H * 64;                               // 2 MB
    int* bcur = (int*)(tabh + (size_t)TAB_BINS * 64);                  // 196
    int* bofs = bcur + NBUCK;                                          // 197
    uintptr_t p = (uintptr_t)(bofs + NBUCK + 1);
    p = (p + 15) & ~(uintptr_t)15;
    uint2* ebuf = (uint2*)p;                                           // 196*6144*8 = 9.6 MB
    uint2* rcb  = ebuf + (size_t)NBUCK * REGION_CAP;                   // 6.4 MB

    const int* row = eidx;
    const int* col = eidx + N_EDGES;

    // bucketed CSR build (with per-edge table bin, layer-independent)
    hipMemsetAsync(bcur, 0, NBUCK * sizeof(int), stream);
    hipLaunchKernelGGL(bscatter_kernel,
                       dim3((N_EDGES + SCAT_BLK_EDGES - 1) / SCAT_BLK_EDGES), dim3(256),
                       0, stream, row, col, pos, bcur, ebuf);
    hipLaunchKernelGGL(bscan_kernel, dim3(1), dim3(256), 0, stream, bcur, bofs);
    hipLaunchKernelGGL(bsort_kernel, dim3(NBUCK), dim3(256), 0, stream,
                       ebuf, bcur, bofs, rcb);

    hipLaunchKernelGGL(lin0_kernel, dim3((N_NODES + 31) / 32), dim3(256), 0, stream,
                       x, W_lin, b_lin, hhf);

    hipMemsetAsync(d_out, 0, (size_t)NUM_GRAPHS * C_H * sizeof(float), stream);

    const int agg_n16 = (int)((size_t)N_NODES * C_H * sizeof(float) / 16);  // 1,600,000
    for (int l = 0; l < 3; ++l) {
        const float* Wc = (const float*)d_in[6 + l * 6 + 0];
        const float* bc = (const float*)d_in[6 + l * 6 + 1];
        const float* Wn = (const float*)d_in[6 + l * 6 + 2];
        const float* bn = (const float*)d_in[6 + l * 6 + 3];
        const float* g  = (const float*)d_in[6 + l * 6 + 4];
        const float* be = (const float*)d_in[6 + l * 6 + 5];

        hipLaunchKernelGGL(build_table_kernel, dim3(TAB_BINS * 64 / 256), dim3(256), 0, stream,
                           Wc, bc, tabh);
        hipLaunchKernelGGL(zero_kernel, dim3(2048), dim3(256), 0, stream,
                           (uint4*)agg, agg_n16);
        hipLaunchKernelGGL(aggregate_kernel, dim3(NCHUNK / 4), dim3(256), 0, stream,
                           hhf, rcb, tabh, agg);
        hipLaunchKernelGGL(cvt_wn_kernel, dim3((C_H * 64 + 255) / 256), dim3(256), 0, stream,
                           Wn, Wnh);
        if (l < 2) {
            hipLaunchKernelGGL(HIP_KERNEL_NAME(node_kernel<0>),
                               dim3((N_NODES + 31) / 32), dim3(256), 0, stream,
                               hhf, (const float2*)agg, Wnh, bn, g, be, batch, (float*)d_out);
        } else {
            hipLaunchKernelGGL(HIP_KERNEL_NAME(node_kernel<1>),
                               dim3((N_NODES + 31) / 32), dim3(256), 0, stream,
                               hhf, (const float2*)agg, Wnh, bn, g, be, batch, (float*)d_out);
        }
    }
}

// Round 12
// 280.622 us; speedup vs baseline: 1.1472x; 1.1472x over previous
//
#include <hip/hip_runtime.h>
#include <hip/hip_fp16.h>
#include <math.h>

#define N_NODES 50000
#define N_EDGES 800000
#define NUM_GRAPHS 256
#define C_IN 64
#define C_H 128
#define D_COUNT 9
#define LRELU_SLOPE 0.01f
#define TAB_BINS 8192
#define TAB_SCALE 1024.0f                  // bins per unit distance, covers d in [0,8)
#define WEDGES 64                          // edges per wave
#define NCHUNK (N_EDGES / WEDGES)          // 12500 wave-chunks
#define NBUCK ((N_NODES + 255) / 256)      // 196 coarse buckets (col>>8)
#define REGION_CAP 6144                    // per-bucket region capacity (mean 4096, +32 sigma)
#define SCAT_BLK_EDGES 2048
// prep_kernel grid partition
#define TBLK (TAB_BINS * 64 / 256)         // 2048 blocks: radial table
#define WNBLK (C_H * 64 / 256)             // 32 blocks: Wn cvt
#define ZBLK 1024                          // 1024 blocks: zero agg (grid-stride)

__device__ __forceinline__ float fast_rcp(float x) { return __builtin_amdgcn_rcpf(x); }
__device__ __forceinline__ __half2 u2h2(unsigned int u) { return __builtin_bit_cast(__half2, u); }
__device__ __forceinline__ unsigned int h22u(__half2 h) { return __builtin_bit_cast(unsigned int, h); }

// packed fp16 atomic add (gfx90a+ global_atomic_pk_add_f16, no return)
__device__ __forceinline__ void atomic_pk_add_h2(unsigned int* addr, unsigned int val) {
    asm volatile("global_atomic_pk_add_f16 %0, %1, off"
                 :: "v"(addr), "v"(val) : "memory");
}

// ---------------- bucketed CSR build (once; edge structure shared by all 3 layers) ---------
__global__ __launch_bounds__(256) void bscatter_kernel(
        const int* __restrict__ row, const int* __restrict__ col,
        const float* __restrict__ pos, int* __restrict__ bcur, uint2* __restrict__ ebuf) {
    __shared__ int lhist[NBUCK];
    __shared__ int lcur[NBUCK];
    const int t = threadIdx.x;
    const int e0 = blockIdx.x * SCAT_BLK_EDGES;
    for (int i = t; i < NBUCK; i += 256) lhist[i] = 0;
    __syncthreads();

    int myb[8];
    uint2 myrec[8];
#pragma unroll
    for (int s = 0; s < 8; ++s) {
        const int e = e0 + s * 256 + t;
        if (e < N_EDGES) {
            const int r = row[e];
            const int c = col[e];
            const float dx = pos[r * 3 + 0] - pos[c * 3 + 0];
            const float dy = pos[r * 3 + 1] - pos[c * 3 + 1];
            const float dz = pos[r * 3 + 2] - pos[c * 3 + 2];
            const float d = sqrtf(dx * dx + dy * dy + dz * dz);
            int bin = (int)(d * TAB_SCALE);
            bin = bin < TAB_BINS - 1 ? bin : TAB_BINS - 1;  // radial saturates beyond table
            myb[s] = c >> 8;
            myrec[s] = make_uint2((unsigned int)r | ((unsigned int)c << 16),
                                  (unsigned int)bin);
            atomicAdd(&lhist[myb[s]], 1);
        } else {
            myb[s] = -1;
        }
    }
    __syncthreads();
    for (int i = t; i < NBUCK; i += 256)
        lcur[i] = (lhist[i] > 0) ? atomicAdd(&bcur[i], lhist[i]) : 0;
    __syncthreads();
#pragma unroll
    for (int s = 0; s < 8; ++s) {
        if (myb[s] >= 0) {
            const int p = atomicAdd(&lcur[myb[s]], 1);
            ebuf[(size_t)myb[s] * REGION_CAP + p] = myrec[s];
        }
    }
}

// per-bucket LDS counting sort by col&255; bucket offsets recomputed in-block (196 ints)
__global__ __launch_bounds__(256) void bsort_kernel(
        const uint2* __restrict__ ebuf, const int* __restrict__ bcur,
        uint2* __restrict__ rcb) {
    __shared__ uint2 se[REGION_CAP];   // 48 KB
    __shared__ int lhist[256];
    __shared__ int lcur[256];
    __shared__ int csc[256];
    const int b = blockIdx.x;
    const int t = threadIdx.x;
    // inclusive scan of all bucket counts -> this bucket's output base
    csc[t] = (t < NBUCK) ? bcur[t] : 0;
    __syncthreads();
    for (int d = 1; d < 256; d <<= 1) {
        const int x = (t >= d) ? csc[t - d] : 0;
        __syncthreads();
        csc[t] += x;
        __syncthreads();
    }
    const int dbase = (b == 0) ? 0 : csc[b - 1];
    const int n = bcur[b];

    const uint2* src = ebuf + (size_t)b * REGION_CAP;
    for (int i = t; i < n; i += 256) se[i] = src[i];
    lhist[t] = 0;
    __syncthreads();
    for (int i = t; i < n; i += 256)
        atomicAdd(&lhist[(se[i].x >> 16) & 255u], 1);
    __syncthreads();
    int v = lhist[t];
    int sv = v;
    lcur[t] = v;
    __syncthreads();
    for (int d = 1; d < 256; d <<= 1) {
        const int x = (t >= d) ? lcur[t - d] : 0;
        __syncthreads();
        lcur[t] += x;
        __syncthreads();
        sv = lcur[t];
    }
    __syncthreads();
    lcur[t] = sv - v;  // exclusive
    __syncthreads();
    for (int i = t; i < n; i += 256) {
        const uint2 e = se[i];
        const int dst = atomicAdd(&lcur[(e.x >> 16) & 255u], 1);
        rcb[dbase + dst] = e;
    }
}

// ---------------- per-layer prep: radial table + Wn cvt + agg zero (one dispatch) ----------
__global__ __launch_bounds__(256) void prep_kernel(
        const float* __restrict__ Wc, const float* __restrict__ bc,
        unsigned int* __restrict__ tabh,
        const float* __restrict__ Wn, unsigned int* __restrict__ Wnh,
        uint4* __restrict__ aggz) {
    const int b = blockIdx.x;
    const int t = threadIdx.x;
    if (b < TBLK) {
        // radial table: tabh[bin][lane] = half2 radial(d at bin center)
        const int idx = b * 256 + t;
        const int lane = idx & 63;
        const int bin = idx >> 6;
        const float d = ((float)bin + 0.5f) * (1.0f / TAB_SCALE);
        float v[2];
#pragma unroll
        for (int p = 0; p < 2; ++p) {
            const int c = 2 * lane + p;
            float a = bc[c];
#pragma unroll
            for (int k = 0; k < D_COUNT; ++k) {
                const float u = (d - 0.75f * (float)k) * 1.5f;  // mu=0.75k, 1/sigma=1.5
                a = fmaf(__expf(-u * u), Wc[k * C_H + c], a);
            }
            v[p] = a * fast_rcp(1.0f + __expf(-a));
        }
        tabh[idx] = h22u(__floats2half2_rn(v[0], v[1]));
    } else if (b < TBLK + WNBLK) {
        // Wn -> half2 pairs
        const int i = (b - TBLK) * 256 + t;
        const int k = i >> 6, p = i & 63;
        Wnh[i] = h22u(__floats2half2_rn(Wn[k * C_H + 2 * p], Wn[k * C_H + 2 * p + 1]));
    } else {
        // zero agg (half2 buffer, 12.8 MB): grid-stride uint4
        const int n16 = N_NODES * 16;  // N_NODES*64 uints / 4 per uint4
        const int stride = ZBLK * 256;
        for (int i = (b - TBLK - WNBLK) * 256 + t; i < n16; i += stride)
            aggz[i] = make_uint4(0u, 0u, 0u, 0u);
    }
}

// ---------------- hhf = half2(silu(x @ W_lin + b_lin)) -------------------------------------
__global__ __launch_bounds__(256) void lin0_kernel(
        const float* __restrict__ x, const float* __restrict__ W,
        const float* __restrict__ b, unsigned int* __restrict__ hhf) {
    __shared__ float xs[32][C_IN];
    const int node0 = blockIdx.x * 32;
    const int t = threadIdx.x;
    for (int i = t * 4; i < 32 * C_IN; i += 256 * 4) {
        const int n = i >> 6;
        const int c = i & 63;
        if (node0 + n < N_NODES)
            *(float4*)&xs[n][c] = *(const float4*)&x[(size_t)(node0 + n) * C_IN + c];
    }
    __syncthreads();
    const int wv = t >> 6;
    const int lane = t & 63;
    const int nb = wv * 8;
    const float2 b2 = *(const float2*)&b[2 * lane];
    float2 acc[8];
#pragma unroll
    for (int n = 0; n < 8; ++n) acc[n] = b2;
    for (int k = 0; k < C_IN; k += 4) {
        const float2 w0 = *(const float2*)&W[(size_t)(k + 0) * C_H + 2 * lane];
        const float2 w1 = *(const float2*)&W[(size_t)(k + 1) * C_H + 2 * lane];
        const float2 w2 = *(const float2*)&W[(size_t)(k + 2) * C_H + 2 * lane];
        const float2 w3 = *(const float2*)&W[(size_t)(k + 3) * C_H + 2 * lane];
#pragma unroll
        for (int n = 0; n < 8; ++n) {
            const float4 sv = *(const float4*)&xs[nb + n][k];
            acc[n].x = fmaf(sv.x, w0.x, acc[n].x); acc[n].y = fmaf(sv.x, w0.y, acc[n].y);
            acc[n].x = fmaf(sv.y, w1.x, acc[n].x); acc[n].y = fmaf(sv.y, w1.y, acc[n].y);
            acc[n].x = fmaf(sv.z, w2.x, acc[n].x); acc[n].y = fmaf(sv.z, w2.y, acc[n].y);
            acc[n].x = fmaf(sv.w, w3.x, acc[n].x); acc[n].y = fmaf(sv.w, w3.y, acc[n].y);
        }
    }
#pragma unroll
    for (int n = 0; n < 8; ++n) {
        const int node = node0 + nb + n;
        if (node < N_NODES) {
            const float ax = acc[n].x, ay = acc[n].y;
            const float sx = ax * fast_rcp(1.0f + __expf(-ax));
            const float sy = ay * fast_rcp(1.0f + __expf(-ay));
            hhf[(size_t)node * 64 + lane] = h22u(__floats2half2_rn(sx, sy));
        }
    }
}

// ---------------- edge-parallel gather-aggregate (table radial, fp16 h, fp16 agg) ----------
__global__ __launch_bounds__(256) void aggregate_kernel(
        const unsigned int* __restrict__ hhf, const uint2* __restrict__ rcb,
        const unsigned int* __restrict__ tabh, unsigned int* __restrict__ aggh) {
    __shared__ uint2 meta[4][WEDGES];   // 2 KB/block
    const int t = threadIdx.x;
    const int lane = t & 63;
    const int wv = t >> 6;
    const int base = (blockIdx.x * 4 + wv) * WEDGES;

    const __half2 hzero = __floats2half2_rn(0.0f, 0.0f);

    meta[wv][lane] = rcb[base + lane];
    asm volatile("s_waitcnt lgkmcnt(0)" ::: "memory");
    __builtin_amdgcn_sched_barrier(0);
    __builtin_amdgcn_wave_barrier();

    unsigned int huA[8], huB[8];
    unsigned int tvA[8], tvB[8];
    int colA[8], colB[8];
    __half2 acc2 = hzero;
    float2 accf = make_float2(0.0f, 0.0f);
    int sCur;
    bool first = true;

#define LOADG(g, HU, TV, CO)                                                  \
    {                                                                         \
        _Pragma("unroll")                                                     \
        for (int u = 0; u < 8; ++u) {                                         \
            const uint2 m = meta[wv][(g) * 8 + u];                            \
            const unsigned int rcu = __builtin_amdgcn_readfirstlane(m.x);     \
            const int sBin = __builtin_amdgcn_readfirstlane((int)m.y);        \
            const int sRow = (int)(rcu & 0xffffu);                            \
            CO[u] = (int)(rcu >> 16);                                         \
            HU[u] = hhf[(size_t)sRow * 64 + lane];                            \
            TV[u] = tabh[(size_t)sBin * 64 + lane];                           \
        }                                                                     \
    }

#define COMPUTEG(g, HU, TV, CO)                                               \
    {                                                                         \
        _Pragma("unroll")                                                     \
        for (int u = 0; u < 8; ++u) {                                         \
            if (CO[u] != sCur) {                                              \
                const float2 pf = __half22float2(acc2);                       \
                accf.x += pf.x; accf.y += pf.y; acc2 = hzero;                 \
                unsigned int* dst = &aggh[(size_t)sCur * 64 + lane];          \
                const unsigned int hv = h22u(__floats2half2_rn(accf.x, accf.y)); \
                if (first) {                                                  \
                    atomic_pk_add_h2(dst, hv);                                \
                    first = false;                                            \
                } else {                                                      \
                    *dst = hv;                                                \
                }                                                             \
                accf.x = 0.0f; accf.y = 0.0f;                                 \
                sCur = CO[u];                                                 \
            }                                                                 \
            acc2 = __hfma2(u2h2(HU[u]), u2h2(TV[u]), acc2);                   \
        }                                                                     \
        const float2 pg = __half22float2(acc2);                               \
        accf.x += pg.x; accf.y += pg.y; acc2 = hzero;                         \
    }

    LOADG(0, huA, tvA, colA);
    sCur = colA[0];
    LOADG(1, huB, tvB, colB);
    COMPUTEG(0, huA, tvA, colA);
    LOADG(2, huA, tvA, colA);
    COMPUTEG(1, huB, tvB, colB);
    LOADG(3, huB, tvB, colB);
    COMPUTEG(2, huA, tvA, colA);
    LOADG(4, huA, tvA, colA);
    COMPUTEG(3, huB, tvB, colB);
    LOADG(5, huB, tvB, colB);
    COMPUTEG(4, huA, tvA, colA);
    LOADG(6, huA, tvA, colA);
    COMPUTEG(5, huB, tvB, colB);
    LOADG(7, huB, tvB, colB);
    COMPUTEG(6, huA, tvA, colA);
    COMPUTEG(7, huB, tvB, colB);

    {
        unsigned int* dst = &aggh[(size_t)sCur * 64 + lane];
        atomic_pk_add_h2(dst, h22u(__floats2half2_rn(accf.x, accf.y)));
    }
#undef LOADG
#undef COMPUTEG
}

// ---------------- node: h' = g*lrelu((h+agg)@Wn + bn)/sqrt(1+eps)+be; POOL fuses add-pool --
template <int POOL>
__global__ __launch_bounds__(256) void node_kernel(
        unsigned int* __restrict__ hhf, const unsigned int* __restrict__ aggh,
        const unsigned int* __restrict__ Wnh, const float* __restrict__ bn,
        const float* __restrict__ g, const float* __restrict__ be,
        const int* __restrict__ batch, float* __restrict__ out) {
    __shared__ unsigned int s[32][C_H];   // dup half2 per (n,k): 16 KB
    const int node0 = blockIdx.x * 32;
    const int t = threadIdx.x;
    for (int i = t; i < 32 * 64; i += 256) {
        const int n = i >> 6;
        const int p = i & 63;
        if (node0 + n < N_NODES) {
            const float2 hv = __half22float2(u2h2(hhf[(size_t)(node0 + n) * 64 + p]));
            const float2 av = __half22float2(u2h2(aggh[(size_t)(node0 + n) * 64 + p]));
            const float vx = hv.x + av.x;
            const float vy = hv.y + av.y;
            s[n][2 * p]     = h22u(__floats2half2_rn(vx, vx));
            s[n][2 * p + 1] = h22u(__floats2half2_rn(vy, vy));
        }
    }
    __syncthreads();
    const int wv = t >> 6;
    const int lane = t & 63;
    const int nb = wv * 8;
    const float2 bn2 = *(const float2*)&bn[2 * lane];
    const __half2 hzero = __floats2half2_rn(0.0f, 0.0f);
    float2 accf[8];
    __half2 acc2[8];
#pragma unroll
    for (int n = 0; n < 8; ++n) { accf[n] = bn2; acc2[n] = hzero; }
    for (int kb = 0; kb < C_H; kb += 32) {
#pragma unroll
        for (int k4 = 0; k4 < 32; k4 += 4) {
            const int k = kb + k4;
            const unsigned int w0 = Wnh[(size_t)(k + 0) * 64 + lane];
            const unsigned int w1 = Wnh[(size_t)(k + 1) * 64 + lane];
            const unsigned int w2 = Wnh[(size_t)(k + 2) * 64 + lane];
            const unsigned int w3 = Wnh[(size_t)(k + 3) * 64 + lane];
#pragma unroll
            for (int n = 0; n < 8; ++n) {
                const uint4 sv = *(const uint4*)&s[nb + n][k];
                acc2[n] = __hfma2(u2h2(sv.x), u2h2(w0), acc2[n]);
                acc2[n] = __hfma2(u2h2(sv.y), u2h2(w1), acc2[n]);
                acc2[n] = __hfma2(u2h2(sv.z), u2h2(w2), acc2[n]);
                acc2[n] = __hfma2(u2h2(sv.w), u2h2(w3), acc2[n]);
            }
        }
#pragma unroll
        for (int n = 0; n < 8; ++n) {
            const float2 pf = __half22float2(acc2[n]);
            accf[n].x += pf.x; accf[n].y += pf.y;
            acc2[n] = hzero;
        }
    }
    const float inv = 0.9999950000374997f;  // 1/sqrt(1+1e-5)
    float2 g2 = *(const float2*)&g[2 * lane];
    g2.x *= inv; g2.y *= inv;
    const float2 be2 = *(const float2*)&be[2 * lane];
    if (POOL == 0) {
#pragma unroll
        for (int n = 0; n < 8; ++n) {
            const int node = node0 + nb + n;
            if (node < N_NODES) {
                float2 v = accf[n];
                v.x = v.x > 0.0f ? v.x : LRELU_SLOPE * v.x;
                v.y = v.y > 0.0f ? v.y : LRELU_SLOPE * v.y;
                const float ox = fmaf(g2.x, v.x, be2.x);
                const float oy = fmaf(g2.y, v.y, be2.y);
                hhf[(size_t)node * 64 + lane] = h22u(__floats2half2_rn(ox, oy));
            }
        }
    } else {
        float2 pacc = make_float2(0.0f, 0.0f);
        int curb = -1;
#pragma unroll
        for (int n = 0; n < 8; ++n) {
            const int node = node0 + nb + n;
            if (node < N_NODES) {
                float2 v = accf[n];
                v.x = v.x > 0.0f ? v.x : LRELU_SLOPE * v.x;
                v.y = v.y > 0.0f ? v.y : LRELU_SLOPE * v.y;
                const float ox = fmaf(g2.x, v.x, be2.x);
                const float oy = fmaf(g2.y, v.y, be2.y);
                const int bb = batch[node];
                if (bb != curb) {
                    if (curb >= 0) {
                        atomicAdd(&out[curb * C_H + 2 * lane], pacc.x);
                        atomicAdd(&out[curb * C_H + 2 * lane + 1], pacc.y);
                    }
                    pacc = make_float2(0.0f, 0.0f);
                    curb = bb;
                }
                pacc.x += ox;
                pacc.y += oy;
            }
        }
        if (curb >= 0) {
            atomicAdd(&out[curb * C_H + 2 * lane], pacc.x);
            atomicAdd(&out[curb * C_H + 2 * lane + 1], pacc.y);
        }
    }
}

extern "C" void kernel_launch(void* const* d_in, const int* in_sizes, int n_in,
                              void* d_out, int out_size, void* d_ws, size_t ws_size,
                              hipStream_t stream) {
    const float* x     = (const float*)d_in[0];
    const float* pos   = (const float*)d_in[1];
    const int*   eidx  = (const int*)d_in[2];
    const int*   batch = (const int*)d_in[3];
    const float* W_lin = (const float*)d_in[4];
    const float* b_lin = (const float*)d_in[5];

    unsigned int* aggh = (unsigned int*)d_ws;                          // 12.8 MB (half2)
    unsigned int* hhf  = aggh + (size_t)N_NODES * 64;                  // 12.8 MB
    unsigned int* Wnh  = hhf + (size_t)N_NODES * 64;                   // 32 KB
    unsigned int* tabh = Wnh + C_H * 64;                               // 2 MB
    int* bcur = (int*)(tabh + (size_t)TAB_BINS * 64);                  // 196
    uintptr_t p = (uintptr_t)(bcur + NBUCK);
    p = (p + 15) & ~(uintptr_t)15;
    uint2* ebuf = (uint2*)p;                                           // 196*6144*8 = 9.6 MB
    uint2* rcb  = ebuf + (size_t)NBUCK * REGION_CAP;                   // 6.4 MB

    const int* row = eidx;
    const int* col = eidx + N_EDGES;

    // bucketed CSR build (with per-edge table bin, layer-independent)
    hipMemsetAsync(bcur, 0, NBUCK * sizeof(int), stream);
    hipLaunchKernelGGL(bscatter_kernel,
                       dim3((N_EDGES + SCAT_BLK_EDGES - 1) / SCAT_BLK_EDGES), dim3(256),
                       0, stream, row, col, pos, bcur, ebuf);
    hipLaunchKernelGGL(bsort_kernel, dim3(NBUCK), dim3(256), 0, stream,
                       ebuf, bcur, rcb);

    hipLaunchKernelGGL(lin0_kernel, dim3((N_NODES + 31) / 32), dim3(256), 0, stream,
                       x, W_lin, b_lin, hhf);

    hipMemsetAsync(d_out, 0, (size_t)NUM_GRAPHS * C_H * sizeof(float), stream);

    for (int l = 0; l < 3; ++l) {
        const float* Wc = (const float*)d_in[6 + l * 6 + 0];
        const float* bc = (const float*)d_in[6 + l * 6 + 1];
        const float* Wn = (const float*)d_in[6 + l * 6 + 2];
        const float* bn = (const float*)d_in[6 + l * 6 + 3];
        const float* g  = (const float*)d_in[6 + l * 6 + 4];
        const float* be = (const float*)d_in[6 + l * 6 + 5];

        hipLaunchKernelGGL(prep_kernel, dim3(TBLK + WNBLK + ZBLK), dim3(256), 0, stream,
                           Wc, bc, tabh, Wn, Wnh, (uint4*)aggh);
        hipLaunchKernelGGL(aggregate_kernel, dim3(NCHUNK / 4), dim3(256), 0, stream,
                           hhf, rcb, tabh, aggh);
        if (l < 2) {
            hipLaunchKernelGGL(HIP_KERNEL_NAME(node_kernel<0>),
                               dim3((N_NODES + 31) / 32), dim3(256), 0, stream,
                               hhf, aggh, Wnh, bn, g, be, batch, (float*)d_out);
        } else {
            hipLaunchKernelGGL(HIP_KERNEL_NAME(node_kernel<1>),
                               dim3((N_NODES + 31) / 32), dim3(256), 0, stream,
                               hhf, aggh, Wnh, bn, g, be, batch, (float*)d_out);
        }
    }
}

// Round 13
// 268.756 us; speedup vs baseline: 1.1978x; 1.0441x over previous
//
#include <hip/hip_runtime.h>
#include <hip/hip_fp16.h>
#include <math.h>

#define N_NODES 50000
#define N_EDGES 800000
#define NUM_GRAPHS 256
#define C_IN 64
#define C_H 128
#define D_COUNT 9
#define LRELU_SLOPE 0.01f
#define TAB_BINS 8192
#define TAB_SCALE 1024.0f                  // bins per unit distance, covers d in [0,8)
#define WEDGES 64                          // edges per wave
#define NCHUNK (N_EDGES / WEDGES)          // 12500 wave-chunks
#define NBUCK ((N_NODES + 255) / 256)      // 196 coarse buckets (col>>8)
#define REGION_CAP 6144                    // per-bucket region capacity
#define SCAT_BLK_EDGES 2048
// prep_all grid partition
#define TBLK (TAB_BINS * 64 / 256)         // 2048 blocks per radial table
#define WNBLK (C_H * 64 / 256)             // 32 blocks per Wn cvt
#define ZBLK 1024                          // agg zero (grid-stride)

__device__ __forceinline__ float fast_rcp(float x) { return __builtin_amdgcn_rcpf(x); }
__device__ __forceinline__ __half2 u2h2(unsigned int u) { return __builtin_bit_cast(__half2, u); }
__device__ __forceinline__ unsigned int h22u(__half2 h) { return __builtin_bit_cast(unsigned int, h); }

// packed fp16 atomic add (gfx90a+ global_atomic_pk_add_f16, no return)
__device__ __forceinline__ void atomic_pk_add_h2(unsigned int* addr, unsigned int val) {
    asm volatile("global_atomic_pk_add_f16 %0, %1, off"
                 :: "v"(addr), "v"(val) : "memory");
}

// ---------------- bucketed CSR build (once; edge structure shared by all 3 layers) ---------
__global__ __launch_bounds__(256) void bscatter_kernel(
        const int* __restrict__ row, const int* __restrict__ col,
        const float* __restrict__ pos, int* __restrict__ bcur, uint2* __restrict__ ebuf) {
    __shared__ int lhist[NBUCK];
    __shared__ int lcur[NBUCK];
    const int t = threadIdx.x;
    const int e0 = blockIdx.x * SCAT_BLK_EDGES;
    for (int i = t; i < NBUCK; i += 256) lhist[i] = 0;
    __syncthreads();

    int myb[8];
    uint2 myrec[8];
#pragma unroll
    for (int s = 0; s < 8; ++s) {
        const int e = e0 + s * 256 + t;
        if (e < N_EDGES) {
            const int r = row[e];
            const int c = col[e];
            const float dx = pos[r * 3 + 0] - pos[c * 3 + 0];
            const float dy = pos[r * 3 + 1] - pos[c * 3 + 1];
            const float dz = pos[r * 3 + 2] - pos[c * 3 + 2];
            const float d = sqrtf(dx * dx + dy * dy + dz * dz);
            int bin = (int)(d * TAB_SCALE);
            bin = bin < TAB_BINS - 1 ? bin : TAB_BINS - 1;  // radial saturates beyond table
            myb[s] = c >> 8;
            myrec[s] = make_uint2((unsigned int)r | ((unsigned int)c << 16),
                                  (unsigned int)bin);
            atomicAdd(&lhist[myb[s]], 1);
        } else {
            myb[s] = -1;
        }
    }
    __syncthreads();
    for (int i = t; i < NBUCK; i += 256)
        lcur[i] = (lhist[i] > 0) ? atomicAdd(&bcur[i], lhist[i]) : 0;
    __syncthreads();
#pragma unroll
    for (int s = 0; s < 8; ++s) {
        if (myb[s] >= 0) {
            const int p = atomicAdd(&lcur[myb[s]], 1);
            ebuf[(size_t)myb[s] * REGION_CAP + p] = myrec[s];
        }
    }
}

// per-bucket LDS counting sort by col&255; bucket offsets recomputed in-block
__global__ __launch_bounds__(256) void bsort_kernel(
        const uint2* __restrict__ ebuf, const int* __restrict__ bcur,
        uint2* __restrict__ rcb) {
    __shared__ uint2 se[REGION_CAP];   // 48 KB
    __shared__ int lhist[256];
    __shared__ int lcur[256];
    __shared__ int csc[256];
    const int b = blockIdx.x;
    const int t = threadIdx.x;
    csc[t] = (t < NBUCK) ? bcur[t] : 0;
    __syncthreads();
    for (int d = 1; d < 256; d <<= 1) {
        const int x = (t >= d) ? csc[t - d] : 0;
        __syncthreads();
        csc[t] += x;
        __syncthreads();
    }
    const int dbase = (b == 0) ? 0 : csc[b - 1];
    const int n = bcur[b];

    const uint2* src = ebuf + (size_t)b * REGION_CAP;
    for (int i = t; i < n; i += 256) se[i] = src[i];
    lhist[t] = 0;
    __syncthreads();
    for (int i = t; i < n; i += 256)
        atomicAdd(&lhist[(se[i].x >> 16) & 255u], 1);
    __syncthreads();
    int v = lhist[t];
    int sv = v;
    lcur[t] = v;
    __syncthreads();
    for (int d = 1; d < 256; d <<= 1) {
        const int x = (t >= d) ? lcur[t - d] : 0;
        __syncthreads();
        lcur[t] += x;
        __syncthreads();
        sv = lcur[t];
    }
    __syncthreads();
    lcur[t] = sv - v;  // exclusive
    __syncthreads();
    for (int i = t; i < n; i += 256) {
        const uint2 e = se[i];
        const int dst = atomicAdd(&lcur[(e.x >> 16) & 255u], 1);
        rcb[dbase + dst] = e;
    }
}

// ---------------- one-time prep: 3 radial tables + 3 Wn cvt + agg zero ---------------------
__global__ __launch_bounds__(256) void prep_all_kernel(
        const float* __restrict__ Wc1, const float* __restrict__ bc1,
        const float* __restrict__ Wc2, const float* __restrict__ bc2,
        const float* __restrict__ Wc3, const float* __restrict__ bc3,
        const float* __restrict__ Wn1, const float* __restrict__ Wn2,
        const float* __restrict__ Wn3,
        unsigned int* __restrict__ tabh, unsigned int* __restrict__ Wnh,
        uint4* __restrict__ aggz) {
    const int b = blockIdx.x;
    const int t = threadIdx.x;
    if (b < 3 * TBLK) {
        const int l = b / TBLK;
        const float* Wc = (l == 0) ? Wc1 : (l == 1) ? Wc2 : Wc3;
        const float* bc = (l == 0) ? bc1 : (l == 1) ? bc2 : bc3;
        const int idx = (b - l * TBLK) * 256 + t;
        const int lane = idx & 63;
        const int bin = idx >> 6;
        const float d = ((float)bin + 0.5f) * (1.0f / TAB_SCALE);
        float v[2];
#pragma unroll
        for (int p = 0; p < 2; ++p) {
            const int c = 2 * lane + p;
            float a = bc[c];
#pragma unroll
            for (int k = 0; k < D_COUNT; ++k) {
                const float u = (d - 0.75f * (float)k) * 1.5f;  // mu=0.75k, 1/sigma=1.5
                a = fmaf(__expf(-u * u), Wc[k * C_H + c], a);
            }
            v[p] = a * fast_rcp(1.0f + __expf(-a));
        }
        tabh[(size_t)l * TAB_BINS * 64 + idx] = h22u(__floats2half2_rn(v[0], v[1]));
    } else if (b < 3 * TBLK + 3 * WNBLK) {
        const int bb = b - 3 * TBLK;
        const int l = bb / WNBLK;
        const float* Wn = (l == 0) ? Wn1 : (l == 1) ? Wn2 : Wn3;
        const int i = (bb - l * WNBLK) * 256 + t;
        const int k = i >> 6, p = i & 63;
        Wnh[(size_t)l * C_H * 64 + i] =
            h22u(__floats2half2_rn(Wn[k * C_H + 2 * p], Wn[k * C_H + 2 * p + 1]));
    } else {
        const int n16 = N_NODES * 16;
        const int stride = ZBLK * 256;
        for (int i = (b - 3 * TBLK - 3 * WNBLK) * 256 + t; i < n16; i += stride)
            aggz[i] = make_uint4(0u, 0u, 0u, 0u);
    }
}

// ---------------- hhf = half2(silu(x @ W_lin + b_lin)) -------------------------------------
__global__ __launch_bounds__(256) void lin0_kernel(
        const float* __restrict__ x, const float* __restrict__ W,
        const float* __restrict__ b, unsigned int* __restrict__ hhf) {
    __shared__ float xs[32][C_IN];
    const int node0 = blockIdx.x * 32;
    const int t = threadIdx.x;
    for (int i = t * 4; i < 32 * C_IN; i += 256 * 4) {
        const int n = i >> 6;
        const int c = i & 63;
        if (node0 + n < N_NODES)
            *(float4*)&xs[n][c] = *(const float4*)&x[(size_t)(node0 + n) * C_IN + c];
    }
    __syncthreads();
    const int wv = t >> 6;
    const int lane = t & 63;
    const int nb = wv * 8;
    const float2 b2 = *(const float2*)&b[2 * lane];
    float2 acc[8];
#pragma unroll
    for (int n = 0; n < 8; ++n) acc[n] = b2;
    for (int k = 0; k < C_IN; k += 4) {
        const float2 w0 = *(const float2*)&W[(size_t)(k + 0) * C_H + 2 * lane];
        const float2 w1 = *(const float2*)&W[(size_t)(k + 1) * C_H + 2 * lane];
        const float2 w2 = *(const float2*)&W[(size_t)(k + 2) * C_H + 2 * lane];
        const float2 w3 = *(const float2*)&W[(size_t)(k + 3) * C_H + 2 * lane];
#pragma unroll
        for (int n = 0; n < 8; ++n) {
            const float4 sv = *(const float4*)&xs[nb + n][k];
            acc[n].x = fmaf(sv.x, w0.x, acc[n].x); acc[n].y = fmaf(sv.x, w0.y, acc[n].y);
            acc[n].x = fmaf(sv.y, w1.x, acc[n].x); acc[n].y = fmaf(sv.y, w1.y, acc[n].y);
            acc[n].x = fmaf(sv.z, w2.x, acc[n].x); acc[n].y = fmaf(sv.z, w2.y, acc[n].y);
            acc[n].x = fmaf(sv.w, w3.x, acc[n].x); acc[n].y = fmaf(sv.w, w3.y, acc[n].y);
        }
    }
#pragma unroll
    for (int n = 0; n < 8; ++n) {
        const int node = node0 + nb + n;
        if (node < N_NODES) {
            const float ax = acc[n].x, ay = acc[n].y;
            const float sx = ax * fast_rcp(1.0f + __expf(-ax));
            const float sy = ay * fast_rcp(1.0f + __expf(-ay));
            hhf[(size_t)node * 64 + lane] = h22u(__floats2half2_rn(sx, sy));
        }
    }
}

// ---------------- edge-parallel gather-aggregate (table radial, fp16 h, fp16 agg) ----------
// depth-3 pipeline: 24 outstanding gathers/wave hide L2/L3 latency.
__global__ __launch_bounds__(256) void aggregate_kernel(
        const unsigned int* __restrict__ hhf, const uint2* __restrict__ rcb,
        const unsigned int* __restrict__ tabh, unsigned int* __restrict__ aggh) {
    __shared__ uint2 meta[4][WEDGES];   // 2 KB/block
    const int t = threadIdx.x;
    const int lane = t & 63;
    const int wv = t >> 6;
    const int base = (blockIdx.x * 4 + wv) * WEDGES;

    const __half2 hzero = __floats2half2_rn(0.0f, 0.0f);

    meta[wv][lane] = rcb[base + lane];
    asm volatile("s_waitcnt lgkmcnt(0)" ::: "memory");
    __builtin_amdgcn_sched_barrier(0);
    __builtin_amdgcn_wave_barrier();

    unsigned int huA[8], huB[8], huC[8];
    unsigned int tvA[8], tvB[8], tvC[8];
    int colA[8], colB[8], colC[8];
    __half2 acc2 = hzero;
    float2 accf = make_float2(0.0f, 0.0f);
    int sCur;
    bool first = true;

#define LOADG(g, HU, TV, CO)                                                  \
    {                                                                         \
        _Pragma("unroll")                                                     \
        for (int u = 0; u < 8; ++u) {                                         \
            const uint2 m = meta[wv][(g) * 8 + u];                            \
            const unsigned int rcu = __builtin_amdgcn_readfirstlane(m.x);     \
            const int sBin = __builtin_amdgcn_readfirstlane((int)m.y);        \
            const int sRow = (int)(rcu & 0xffffu);                            \
            CO[u] = (int)(rcu >> 16);                                         \
            HU[u] = hhf[(size_t)sRow * 64 + lane];                            \
            TV[u] = tabh[(size_t)sBin * 64 + lane];                           \
        }                                                                     \
    }

#define COMPUTEG(HU, TV, CO)                                                  \
    {                                                                         \
        _Pragma("unroll")                                                     \
        for (int u = 0; u < 8; ++u) {                                         \
            if (CO[u] != sCur) {                                              \
                const float2 pf = __half22float2(acc2);                       \
                accf.x += pf.x; accf.y += pf.y; acc2 = hzero;                 \
                unsigned int* dst = &aggh[(size_t)sCur * 64 + lane];          \
                const unsigned int hv = h22u(__floats2half2_rn(accf.x, accf.y)); \
                if (first) {                                                  \
                    atomic_pk_add_h2(dst, hv);                                \
                    first = false;                                            \
                } else {                                                      \
                    *dst = hv;                                                \
                }                                                             \
                accf.x = 0.0f; accf.y = 0.0f;                                 \
                sCur = CO[u];                                                 \
            }                                                                 \
            acc2 = __hfma2(u2h2(HU[u]), u2h2(TV[u]), acc2);                   \
        }                                                                     \
        const float2 pg = __half22float2(acc2);                               \
        accf.x += pg.x; accf.y += pg.y; acc2 = hzero;                         \
    }

    LOADG(0, huA, tvA, colA);
    LOADG(1, huB, tvB, colB);
    LOADG(2, huC, tvC, colC);
    sCur = colA[0];
    COMPUTEG(huA, tvA, colA);
    LOADG(3, huA, tvA, colA);
    COMPUTEG(huB, tvB, colB);
    LOADG(4, huB, tvB, colB);
    COMPUTEG(huC, tvC, colC);
    LOADG(5, huC, tvC, colC);
    COMPUTEG(huA, tvA, colA);
    LOADG(6, huA, tvA, colA);
    COMPUTEG(huB, tvB, colB);
    LOADG(7, huB, tvB, colB);
    COMPUTEG(huC, tvC, colC);
    COMPUTEG(huA, tvA, colA);
    COMPUTEG(huB, tvB, colB);

    {
        unsigned int* dst = &aggh[(size_t)sCur * 64 + lane];
        atomic_pk_add_h2(dst, h22u(__floats2half2_rn(accf.x, accf.y)));
    }
#undef LOADG
#undef COMPUTEG
}

// ---------------- node: h' = g*lrelu((h+agg)@Wn + bn)/sqrt(1+eps)+be ------------------------
// ZERO=1: re-zero aggh after reading (replaces separate zero sweep for next layer).
// POOL=1 (last layer): skip h-store, run-accumulate into out[batch[node]].
template <int POOL, int ZERO>
__global__ __launch_bounds__(256) void node_kernel(
        unsigned int* __restrict__ hhf, unsigned int* __restrict__ aggh,
        const unsigned int* __restrict__ Wnh, const float* __restrict__ bn,
        const float* __restrict__ g, const float* __restrict__ be,
        const int* __restrict__ batch, float* __restrict__ out) {
    __shared__ unsigned int s[32][C_H];   // dup half2 per (n,k): 16 KB
    const int node0 = blockIdx.x * 32;
    const int t = threadIdx.x;
    for (int i = t; i < 32 * 64; i += 256) {
        const int n = i >> 6;
        const int p = i & 63;
        if (node0 + n < N_NODES) {
            const float2 hv = __half22float2(u2h2(hhf[(size_t)(node0 + n) * 64 + p]));
            const float2 av = __half22float2(u2h2(aggh[(size_t)(node0 + n) * 64 + p]));
            if (ZERO) aggh[(size_t)(node0 + n) * 64 + p] = 0u;
            const float vx = hv.x + av.x;
            const float vy = hv.y + av.y;
            s[n][2 * p]     = h22u(__floats2half2_rn(vx, vx));
            s[n][2 * p + 1] = h22u(__floats2half2_rn(vy, vy));
        }
    }
    __syncthreads();
    const int wv = t >> 6;
    const int lane = t & 63;
    const int nb = wv * 8;
    const float2 bn2 = *(const float2*)&bn[2 * lane];
    const __half2 hzero = __floats2half2_rn(0.0f, 0.0f);
    float2 accf[8];
    __half2 acc2[8];
#pragma unroll
    for (int n = 0; n < 8; ++n) { accf[n] = bn2; acc2[n] = hzero; }
    for (int kb = 0; kb < C_H; kb += 32) {
#pragma unroll
        for (int k4 = 0; k4 < 32; k4 += 4) {
            const int k = kb + k4;
            const unsigned int w0 = Wnh[(size_t)(k + 0) * 64 + lane];
            const unsigned int w1 = Wnh[(size_t)(k + 1) * 64 + lane];
            const unsigned int w2 = Wnh[(size_t)(k + 2) * 64 + lane];
            const unsigned int w3 = Wnh[(size_t)(k + 3) * 64 + lane];
#pragma unroll
            for (int n = 0; n < 8; ++n) {
                const uint4 sv = *(const uint4*)&s[nb + n][k];
                acc2[n] = __hfma2(u2h2(sv.x), u2h2(w0), acc2[n]);
                acc2[n] = __hfma2(u2h2(sv.y), u2h2(w1), acc2[n]);
                acc2[n] = __hfma2(u2h2(sv.z), u2h2(w2), acc2[n]);
                acc2[n] = __hfma2(u2h2(sv.w), u2h2(w3), acc2[n]);
            }
        }
#pragma unroll
        for (int n = 0; n < 8; ++n) {
            const float2 pf = __half22float2(acc2[n]);
            accf[n].x += pf.x; accf[n].y += pf.y;
            acc2[n] = hzero;
        }
    }
    const float inv = 0.9999950000374997f;  // 1/sqrt(1+1e-5)
    float2 g2 = *(const float2*)&g[2 * lane];
    g2.x *= inv; g2.y *= inv;
    const float2 be2 = *(const float2*)&be[2 * lane];
    if (POOL == 0) {
#pragma unroll
        for (int n = 0; n < 8; ++n) {
            const int node = node0 + nb + n;
            if (node < N_NODES) {
                float2 v = accf[n];
                v.x = v.x > 0.0f ? v.x : LRELU_SLOPE * v.x;
                v.y = v.y > 0.0f ? v.y : LRELU_SLOPE * v.y;
                const float ox = fmaf(g2.x, v.x, be2.x);
                const float oy = fmaf(g2.y, v.y, be2.y);
                hhf[(size_t)node * 64 + lane] = h22u(__floats2half2_rn(ox, oy));
            }
        }
    } else {
        float2 pacc = make_float2(0.0f, 0.0f);
        int curb = -1;
#pragma unroll
        for (int n = 0; n < 8; ++n) {
            const int node = node0 + nb + n;
            if (node < N_NODES) {
                float2 v = accf[n];
                v.x = v.x > 0.0f ? v.x : LRELU_SLOPE * v.x;
                v.y = v.y > 0.0f ? v.y : LRELU_SLOPE * v.y;
                const float ox = fmaf(g2.x, v.x, be2.x);
                const float oy = fmaf(g2.y, v.y, be2.y);
                const int bb = batch[node];
                if (bb != curb) {
                    if (curb >= 0) {
                        atomicAdd(&out[curb * C_H + 2 * lane], pacc.x);
                        atomicAdd(&out[curb * C_H + 2 * lane + 1], pacc.y);
                    }
                    pacc = make_float2(0.0f, 0.0f);
                    curb = bb;
                }
                pacc.x += ox;
                pacc.y += oy;
            }
        }
        if (curb >= 0) {
            atomicAdd(&out[curb * C_H + 2 * lane], pacc.x);
            atomicAdd(&out[curb * C_H + 2 * lane + 1], pacc.y);
        }
    }
}

extern "C" void kernel_launch(void* const* d_in, const int* in_sizes, int n_in,
                              void* d_out, int out_size, void* d_ws, size_t ws_size,
                              hipStream_t stream) {
    const float* x     = (const float*)d_in[0];
    const float* pos   = (const float*)d_in[1];
    const int*   eidx  = (const int*)d_in[2];
    const int*   batch = (const int*)d_in[3];
    const float* W_lin = (const float*)d_in[4];
    const float* b_lin = (const float*)d_in[5];

    unsigned int* aggh = (unsigned int*)d_ws;                          // 12.8 MB (half2)
    unsigned int* hhf  = aggh + (size_t)N_NODES * 64;                  // 12.8 MB
    unsigned int* Wnh  = hhf + (size_t)N_NODES * 64;                   // 3 * 32 KB
    unsigned int* tabh = Wnh + 3 * C_H * 64;                           // 3 * 2 MB
    int* bcur = (int*)(tabh + 3 * (size_t)TAB_BINS * 64);              // 196
    uintptr_t p = (uintptr_t)(bcur + NBUCK);
    p = (p + 15) & ~(uintptr_t)15;
    uint2* ebuf = (uint2*)p;                                           // 9.6 MB
    uint2* rcb  = ebuf + (size_t)NBUCK * REGION_CAP;                   // 6.4 MB

    const int* row = eidx;
    const int* col = eidx + N_EDGES;

    // bucketed CSR build (with per-edge table bin, layer-independent)
    hipMemsetAsync(bcur, 0, NBUCK * sizeof(int), stream);
    hipLaunchKernelGGL(bscatter_kernel,
                       dim3((N_EDGES + SCAT_BLK_EDGES - 1) / SCAT_BLK_EDGES), dim3(256),
                       0, stream, row, col, pos, bcur, ebuf);
    hipLaunchKernelGGL(bsort_kernel, dim3(NBUCK), dim3(256), 0, stream,
                       ebuf, bcur, rcb);

    // one-time prep: all 3 radial tables, all 3 Wn cvts, zero agg
    hipLaunchKernelGGL(prep_all_kernel, dim3(3 * TBLK + 3 * WNBLK + ZBLK), dim3(256),
                       0, stream,
                       (const float*)d_in[6],  (const float*)d_in[7],
                       (const float*)d_in[12], (const float*)d_in[13],
                       (const float*)d_in[18], (const float*)d_in[19],
                       (const float*)d_in[8],  (const float*)d_in[14],
                       (const float*)d_in[20],
                       tabh, Wnh, (uint4*)aggh);

    hipLaunchKernelGGL(lin0_kernel, dim3((N_NODES + 31) / 32), dim3(256), 0, stream,
                       x, W_lin, b_lin, hhf);

    hipMemsetAsync(d_out, 0, (size_t)NUM_GRAPHS * C_H * sizeof(float), stream);

    for (int l = 0; l < 3; ++l) {
        const float* bn = (const float*)d_in[6 + l * 6 + 3];
        const float* g  = (const float*)d_in[6 + l * 6 + 4];
        const float* be = (const float*)d_in[6 + l * 6 + 5];
        unsigned int* tab_l = tabh + (size_t)l * TAB_BINS * 64;
        unsigned int* Wnh_l = Wnh + (size_t)l * C_H * 64;

        hipLaunchKernelGGL(aggregate_kernel, dim3(NCHUNK / 4), dim3(256), 0, stream,
                           hhf, rcb, tab_l, aggh);
        if (l == 0) {
            hipLaunchKernelGGL(HIP_KERNEL_NAME(node_kernel<0, 1>),
                               dim3((N_NODES + 31) / 32), dim3(256), 0, stream,
                               hhf, aggh, Wnh_l, bn, g, be, batch, (float*)d_out);
        } else if (l == 1) {
            hipLaunchKernelGGL(HIP_KERNEL_NAME(node_kernel<0, 1>),
                               dim3((N_NODES + 31) / 32), dim3(256), 0, stream,
                               hhf, aggh, Wnh_l, bn, g, be, batch, (float*)d_out);
        } else {
            hipLaunchKernelGGL(HIP_KERNEL_NAME(node_kernel<1, 0>),
                               dim3((N_NODES + 31) / 32), dim3(256), 0, stream,
                               hhf, aggh, Wnh_l, bn, g, be, batch, (float*)d_out);
        }
    }
}